// Round 1
// baseline (688.706 us; speedup 1.0000x reference)
//
#include <hip/hip_runtime.h>
#include <hip/hip_bf16.h>

#define NB 2
#define NS 2048
#define ND 1024
#define NH 16
#define NDK 64
#define NHI 4
#define NDI 64
#define NTOPK 512

typedef unsigned int u32;

typedef __attribute__((ext_vector_type(8))) short bf16x8;
typedef __attribute__((ext_vector_type(4))) short bf16x4;
typedef __attribute__((ext_vector_type(4))) float f32x4;

__device__ __forceinline__ short f2bf(float f) {
    u32 u = __float_as_uint(f);
    u += 0x7fffu + ((u >> 16) & 1u);   // round-to-nearest-even bf16
    return (short)(u >> 16);
}
__device__ __forceinline__ float bf2f(short h) {
    return __uint_as_float(((u32)(unsigned short)h) << 16);
}
__device__ __forceinline__ float4 fma4(float4 a, float4 b, float4 c) {
    float4 r;
    r.x = fmaf(a.x, b.x, c.x); r.y = fmaf(a.y, b.y, c.y);
    r.z = fmaf(a.z, b.z, c.z); r.w = fmaf(a.w, b.w, c.w);
    return r;
}

#define TR64(dst, addr, OFF) \
    asm volatile("ds_read_b64_tr_b16 %0, %1 offset:" OFF : "=v"(dst) : "v"(addr))

// ============================ Kernel 0 =====================================
__global__ __launch_bounds__(256) void k0_split(
    const float* __restrict__ K, const float* __restrict__ V,
    short* __restrict__ Khl, short* __restrict__ Vhl)
{
    int e = blockIdx.x*256 + threadIdx.x;     // e < NB*NS*NDK
    int row = e >> 6, d = e & 63;
    float kf = K[e], vf = V[e];
    short kh = f2bf(kf), vh = f2bf(vf);
    short kl = f2bf(kf - bf2f(kh)), vl = f2bf(vf - bf2f(vh));
    Khl[(size_t)row*128 + d]      = kh;
    Khl[(size_t)row*128 + 64 + d] = kl;
    Vhl[(size_t)row*128 + d]      = vh;
    Vhl[(size_t)row*128 + 64 + d] = vl;
}

// ============================ Kernel 1 =====================================
// np-mimic: proj = x@W (OpenBLAS sequential-k FMA chains, kc=384 panels
// (P1+P2)+P3, +bias), then numpy-pairwise LayerNorm. BIT-EXACT chains.
// v2: x is wave-uniform -> read via the SCALAR path (uniform global float4
// loads -> s_load_dwordx4), NOT LDS broadcasts. The LDS pipe (1/CU) was 2-6x
// oversubscribed vs 4 SIMDs; scalar loads free it entirely. LDS is now only
// the 8 KB proj buffer for the LN epilogue. W streams on VMEM as before.
#define ROWS1 8
__global__ __launch_bounds__(256) void k1_proj_ln(
    const float* __restrict__ x, const float* __restrict__ Wq, const float* __restrict__ bq,
    const float* __restrict__ Wk, const float* __restrict__ bk,
    const float* __restrict__ gamma, const float* __restrict__ beta,
    float* __restrict__ q_index, float* __restrict__ k_index)
{
    __shared__ float projf[ROWS1*256];              // 8 KB
    const int tid = threadIdx.x;
    const int m = blockIdx.x & 1;                   // 0 = Wq, 1 = Wk
    const int row0 = (blockIdx.x >> 1) * ROWS1;
    const float* __restrict__ W    = m ? Wk : Wq;
    const float* __restrict__ bias = m ? bk : bq;
    const int c = tid;
    const float4* __restrict__ xg =
        reinterpret_cast<const float4*>(x) + (size_t)row0 * (ND/4);

    float acc[ROWS1];
    const int panel_lo4[3] = {0, 96, 192};
    const int panel_hi4[3] = {96, 192, 256};
    #pragma unroll
    for (int p = 0; p < 3; ++p) {
        float P[ROWS1];
        #pragma unroll
        for (int r = 0; r < ROWS1; ++r) P[r] = 0.f;
        for (int k4 = panel_lo4[p]; k4 < panel_hi4[p]; ++k4) {
            float4 xv[ROWS1];
            #pragma unroll
            for (int r = 0; r < ROWS1; ++r)
                xv[r] = xg[r*256 + k4];             // uniform addr -> s_load
            #pragma unroll
            for (int kk = 0; kk < 4; ++kk) {
                float wv = W[(size_t)(k4*4 + kk)*256 + c];
                #pragma unroll
                for (int r = 0; r < ROWS1; ++r) {
                    float xs_ = (kk == 0) ? xv[r].x : (kk == 1) ? xv[r].y : (kk == 2) ? xv[r].z : xv[r].w;
                    P[r] = fmaf(xs_, wv, P[r]);
                }
            }
        }
        #pragma unroll
        for (int r = 0; r < ROWS1; ++r) {
            if (p == 0) acc[r] = P[r];
            else        acc[r] = acc[r] + P[r];
        }
    }
    float bv = bias[c];
    #pragma unroll
    for (int r = 0; r < ROWS1; ++r) projf[r*256 + c] = acc[r] + bv;
    __syncthreads();

    // numpy-pairwise LayerNorm (8-accumulator pattern, n=64); 4 heads here
    if (tid < ROWS1*4) {
        const int r = tid >> 2, hd = tid & 3;
        const float* pp = &projf[r*256 + hd*64];
        float rr[8];
        #pragma unroll
        for (int q8 = 0; q8 < 8; ++q8) rr[q8] = pp[q8];
        #pragma unroll
        for (int i = 8; i < 64; i += 8)
            #pragma unroll
            for (int q8 = 0; q8 < 8; ++q8) rr[q8] += pp[i + q8];
        float ssum = ((rr[0]+rr[1]) + (rr[2]+rr[3])) + ((rr[4]+rr[5]) + (rr[6]+rr[7]));
        float mu = ssum / 64.0f;

        #pragma unroll
        for (int q8 = 0; q8 < 8; ++q8) { float dv = pp[q8] - mu; rr[q8] = dv*dv; }
        #pragma unroll
        for (int i = 8; i < 64; i += 8)
            #pragma unroll
            for (int q8 = 0; q8 < 8; ++q8) { float dv = pp[i+q8] - mu; rr[q8] += dv*dv; }
        float vsum = ((rr[0]+rr[1]) + (rr[2]+rr[3])) + ((rr[4]+rr[5]) + (rr[6]+rr[7]));
        float var = vsum / 64.0f;
        float inv = 1.0f / (float)sqrt((double)(var + 1e-5f));

        float* dst = (m ? k_index : q_index)
                     + ((size_t)(row0 + r)) * (NHI*NDI) + hd*64;
        for (int i = 0; i < 64; ++i) {
            float dv = pp[i] - mu;
            float t = dv * inv;
            t = t * gamma[i];
            t = t + beta[i];
            dst[i] = t;
        }
    }
}

// ============================ Kernel 2 =====================================
// np-mimic fp32 scores (npyv-AVX512 contig_two emulation). BIT-EXACT chains.
// v2: NO LDS. A (k_index) rows are wave-uniform -> scalar path (uniform
// 16-float chunks -> s_load_dwordx16 after merging). B (q_index) fragments
// per-lane straight from global into registers, reused across 16 rows.
// Tile: 64 s-rows x 128 t-cols per block; each wave does 32 rows x 64 cols
// in two 16-row halves (caps VGPR <= 128 via __launch_bounds__(256,4)).
__global__ __launch_bounds__(256, 4) void k2_scores(
    const float* __restrict__ q_index, const float* __restrict__ k_index,
    const float* __restrict__ hw, u32* __restrict__ keys)
{
    const int tid  = threadIdx.x;
    const int lane = tid & 63;
    const int w    = tid >> 6;
    const int b    = blockIdx.z;
    const int t0   = blockIdx.x * 128 + (w >> 1) * 64;
    const int s0   = blockIdx.y * 64  + (w & 1) * 32;
    const int tcol = t0 + lane;

    const float* __restrict__ bbase = q_index + ((size_t)b*NS + tcol)*(NHI*NDI);

    #pragma unroll
    for (int half = 0; half < 2; ++half) {
        const int r0 = s0 + half*16;
        float fin[16];
        #pragma unroll
        for (int r = 0; r < 16; ++r) fin[r] = 0.f;

        for (int h = 0; h < NHI; ++h) {
            float4 bf[16];
            #pragma unroll
            for (int q4 = 0; q4 < 16; ++q4)
                bf[q4] = *reinterpret_cast<const float4*>(bbase + h*NDI + q4*4);
            float wgt = hw[h];

            #pragma unroll
            for (int r = 0; r < 16; ++r) {
                const float* __restrict__ ap =
                    k_index + (((size_t)b*NS + r0 + r)*NHI + h)*NDI;
                float4 l0 = {0,0,0,0}, l1 = {0,0,0,0}, l2 = {0,0,0,0}, l3 = {0,0,0,0};
                #pragma unroll
                for (int cc = 0; cc < 4; ++cc) {
                    // uniform addr, 16 consecutive floats -> s_load_dwordx16
                    float4 a0 = *reinterpret_cast<const float4*>(ap + cc*16 + 0);
                    float4 a1 = *reinterpret_cast<const float4*>(ap + cc*16 + 4);
                    float4 a2 = *reinterpret_cast<const float4*>(ap + cc*16 + 8);
                    float4 a3 = *reinterpret_cast<const float4*>(ap + cc*16 + 12);
                    l0 = fma4(a0, bf[cc*4+0], l0);
                    l1 = fma4(a1, bf[cc*4+1], l1);
                    l2 = fma4(a2, bf[cc*4+2], l2);
                    l3 = fma4(a3, bf[cc*4+3], l3);
                }
                float4 u, v2, t2;
                u.x=l0.x+l2.x; u.y=l0.y+l2.y; u.z=l0.z+l2.z; u.w=l0.w+l2.w;
                v2.x=l1.x+l3.x; v2.y=l1.y+l3.y; v2.z=l1.z+l3.z; v2.w=l1.w+l3.w;
                t2.x=u.x+v2.x; t2.y=u.y+v2.y; t2.z=u.z+v2.z; t2.w=u.w+v2.w;
                float s3a = t2.x + t2.z, s3b = t2.y + t2.w;
                float dot = s3a + s3b;
                fin[r] = fmaf(wgt, fmaxf(dot, 0.f), fin[r]);
            }
        }
        #pragma unroll
        for (int r = 0; r < 16; ++r)
            keys[((size_t)b*NS + r0 + r)*NS + tcol] = __float_as_uint(fin[r]);
    }
}

// ============================ Kernel 3 =====================================
// Exact top-512 per row via 4x8-bit radix select on u32 keys (fp32 bits).
// Scans done by WAVE 0 only (in-lane 4-elem suffix/prefix + 6 shfl steps,
// u32-exact, identical outputs) -> ~20 barriers/block instead of ~90.
__global__ __launch_bounds__(256) void k3_select(
    const u32* __restrict__ keys_g, int* __restrict__ top_idx)
{
    __shared__ u32 hist[256];
    __shared__ u32 scan[256];
    __shared__ u32 sel_byte, sel_above;
    const int tid = threadIdx.x;
    const size_t row = blockIdx.x;
    const u32* src = keys_g + row * NS;

    u32 keys[8];
    #pragma unroll
    for (int i = 0; i < 8; ++i) keys[i] = src[tid*8 + i];

    u32 prefix = 0, kk = NTOPK, total_gt = 0;
    #pragma unroll
    for (int pass = 0; pass < 4; ++pass) {
        const int shift = 24 - pass*8;
        const u32 mask_hi = (pass == 0) ? 0u : (0xFFFFFFFFu << (shift + 8));
        hist[tid] = 0;
        __syncthreads();
        #pragma unroll
        for (int i = 0; i < 8; ++i)
            if (((keys[i] ^ prefix) & mask_hi) == 0u)
                atomicAdd(&hist[(keys[i] >> shift) & 255], 1u);
        __syncthreads();
        // inclusive suffix scan over 256 bins, by wave 0 only
        if (tid < 64) {
            u32 v0 = hist[tid*4+0], v1 = hist[tid*4+1], v2 = hist[tid*4+2], v3 = hist[tid*4+3];
            u32 s3 = v3, s2 = v2 + s3, s1 = v1 + s2, s0 = v0 + s1;
            u32 suf = s0;
            #pragma unroll
            for (int o = 1; o < 64; o <<= 1) {
                u32 t = __shfl_down(suf, o, 64);
                if (tid + o < 64) suf += t;
            }
            u32 excl = suf - s0;   // sum over lanes > tid (u32-exact)
            hist[tid*4+0] = s0 + excl;
            hist[tid*4+1] = s1 + excl;
            hist[tid*4+2] = s2 + excl;
            hist[tid*4+3] = s3 + excl;
        }
        __syncthreads();
        if (hist[tid] >= kk && (tid == 255 || hist[tid+1] < kk)) {
            sel_byte = (u32)tid;
            sel_above = (tid == 255) ? 0u : hist[tid+1];
        }
        __syncthreads();
        u32 sb = sel_byte, sa = sel_above;
        prefix |= (sb << shift);
        total_gt += sa;
        kk -= sa;
    }

    const u32 T = prefix;
    const u32 needed = NTOPK - total_gt;

    u32 cgt = 0, ceq = 0;
    #pragma unroll
    for (int i = 0; i < 8; ++i) { cgt += (keys[i] > T); ceq += (keys[i] == T); }
    scan[tid] = (cgt << 16) | ceq;
    __syncthreads();
    // inclusive prefix scan over 256 threads, by wave 0 only
    if (tid < 64) {
        u32 v0 = scan[tid*4+0], v1 = scan[tid*4+1], v2 = scan[tid*4+2], v3 = scan[tid*4+3];
        u32 p0 = v0, p1 = p0 + v1, p2 = p1 + v2, p3 = p2 + v3;
        u32 pre = p3;
        #pragma unroll
        for (int o = 1; o < 64; o <<= 1) {
            u32 t = __shfl_up(pre, o, 64);
            if (tid >= o) pre += t;
        }
        u32 excl = pre - p3;   // sum over lanes < tid
        scan[tid*4+0] = p0 + excl;
        scan[tid*4+1] = p1 + excl;
        scan[tid*4+2] = p2 + excl;
        scan[tid*4+3] = p3 + excl;
    }
    __syncthreads();
    u32 incl = scan[tid];
    u32 gt_pref = (incl >> 16) - cgt;
    u32 eq_pref = (incl & 0xFFFFu) - ceq;

    int* dst = top_idx + row * NTOPK;
    u32 lgt = 0, leq = 0;
    #pragma unroll
    for (int i = 0; i < 8; ++i) {
        int idx = tid*8 + i;
        if (keys[i] > T) {
            u32 eqsel = eq_pref + leq; if (eqsel > needed) eqsel = needed;
            u32 slot = gt_pref + lgt + eqsel;
            if (slot < NTOPK) dst[slot] = idx;
            lgt++;
        } else if (keys[i] == T) {
            u32 er = eq_pref + leq;
            if (er < needed) {
                u32 slot = gt_pref + lgt + er;
                if (slot < NTOPK) dst[slot] = idx;
            }
            leq++;
        }
    }
}

// ============================ Kernel 4 =====================================
// Gathered attention, split-bf16 3-term MFMA, precomputed Khl/Vhl.
__global__ __launch_bounds__(256) void k4_attn_mfma(
    const float* __restrict__ Qg, const short* __restrict__ Khl, const short* __restrict__ Vhl,
    const int* __restrict__ top_idx, float* __restrict__ out)
{
    __shared__ short Ph[NTOPK*16];  // P^T hi [key][head] 16 KB
    __shared__ short Pl[NTOPK*16];  // 16 KB
    __shared__ short Vh[64*64];     // V chunk, subtiled-swizzled, 8 KB
    __shared__ short Vl[64*64];     // 8 KB
    __shared__ float red[2][16][4];
    __shared__ int   idxs[NTOPK];

    const int tid = threadIdx.x;
    const int l = tid & 63, w = tid >> 6;
    const int q = l >> 4, d15 = l & 15;
    const size_t blk = blockIdx.x;
    const int b = (int)(blk >> 11), s = (int)(blk & 2047);

    for (int i = tid; i < NTOPK; i += 256) idxs[i] = top_idx[blk*NTOPK + i];

    // Q A-fragments: row(head)=d15, k = ks*32 + q*8 + j
    bf16x8 qhi[2], qlo[2];
    {
        const float* qp = Qg + (((size_t)b*NH + d15)*NS + s)*NDK + q*8;
        #pragma unroll
        for (int ks = 0; ks < 2; ++ks) {
            float4 f0 = *reinterpret_cast<const float4*>(qp + ks*32);
            float4 f1 = *reinterpret_cast<const float4*>(qp + ks*32 + 4);
            float fv[8] = {f0.x,f0.y,f0.z,f0.w,f1.x,f1.y,f1.z,f1.w};
            #pragma unroll
            for (int jj = 0; jj < 8; ++jj) {
                short hh = f2bf(fv[jj]);
                qhi[ks][jj] = hh;
                qlo[ks][jj] = f2bf(fv[jj] - bf2f(hh));
            }
        }
    }
    __syncthreads();   // idxs ready

    f32x4 sacc[8];
    #pragma unroll
    for (int t = 0; t < 8; ++t) sacc[t] = (f32x4){0.f, 0.f, 0.f, 0.f};

    // ---- QK^T: direct global gather of K fragments ----
    #pragma unroll
    for (int c = 0; c < 4; ++c) {
        #pragma unroll
        for (int t = 0; t < 2; ++t) {
            int key = c*128 + w*32 + t*16 + d15;
            int kidx = idxs[key];
            const short* rowp = Khl + ((size_t)b*NS + kidx)*128;
            int ti = c*2 + t;
            #pragma unroll
            for (int ks = 0; ks < 2; ++ks) {
                bf16x8 kh = *reinterpret_cast<const bf16x8*>(rowp + ks*32 + q*8);
                bf16x8 kl = *reinterpret_cast<const bf16x8*>(rowp + 64 + ks*32 + q*8);
                sacc[ti] = __builtin_amdgcn_mfma_f32_16x16x32_bf16(qhi[ks], kh, sacc[ti], 0, 0, 0);
                sacc[ti] = __builtin_amdgcn_mfma_f32_16x16x32_bf16(qlo[ks], kh, sacc[ti], 0, 0, 0);
                sacc[ti] = __builtin_amdgcn_mfma_f32_16x16x32_bf16(qhi[ks], kl, sacc[ti], 0, 0, 0);
            }
        }
    }

    // ---- prefetch V chunk 0 into regs ----
    bf16x8 vreg[4];
    #pragma unroll
    for (int i = 0; i < 4; ++i) {
        int tt = tid + 256*(i & 3);
        int key = (tt >> 3) & 63, jb = tt & 7, part = tt >> 9;
        vreg[i] = *reinterpret_cast<const bf16x8*>(
            Vhl + ((size_t)b*NS + idxs[0*64 + key])*128 + part*64 + jb*8);
    }

    // ---- softmax: head = q*4 + rg, distributed over 4 waves ----
    float m[4], inv[4];
    #pragma unroll
    for (int rg = 0; rg < 4; ++rg) {
        float mm = -3.4e38f;
        #pragma unroll
        for (int t = 0; t < 8; ++t) { sacc[t][rg] *= 0.125f; mm = fmaxf(mm, sacc[t][rg]); }
        #pragma unroll
        for (int o = 1; o <= 8; o <<= 1) mm = fmaxf(mm, __shfl_xor(mm, o));
        m[rg] = mm;
    }
    if (d15 == 0) {
        #pragma unroll
        for (int rg = 0; rg < 4; ++rg) red[0][q*4 + rg][w] = m[rg];
    }
    __syncthreads();
    float sum[4];
    #pragma unroll
    for (int rg = 0; rg < 4; ++rg) {
        int hh = q*4 + rg;
        float g = fmaxf(fmaxf(red[0][hh][0], red[0][hh][1]),
                        fmaxf(red[0][hh][2], red[0][hh][3]));
        float ss = 0.f;
        #pragma unroll
        for (int t = 0; t < 8; ++t) { float p = __expf(sacc[t][rg] - g); sacc[t][rg] = p; ss += p; }
        #pragma unroll
        for (int o = 1; o <= 8; o <<= 1) ss += __shfl_xor(ss, o);
        sum[rg] = ss;
    }
    if (d15 == 0) {
        #pragma unroll
        for (int rg = 0; rg < 4; ++rg) red[1][q*4 + rg][w] = sum[rg];
    }
    __syncthreads();
    #pragma unroll
    for (int rg = 0; rg < 4; ++rg) {
        int hh = q*4 + rg;
        inv[rg] = 1.f / (red[1][hh][0] + red[1][hh][1] + red[1][hh][2] + red[1][hh][3]);
    }

    // ---- write P transposed [key][16 heads], split bf16, b64 writes ----
    #pragma unroll
    for (int t = 0; t < 8; ++t) {
        int key = (t >> 1)*128 + w*32 + (t & 1)*16 + d15;
        bf16x4 h4, l4;
        #pragma unroll
        for (int rg = 0; rg < 4; ++rg) {
            float p = sacc[t][rg] * inv[rg];
            short ph_ = f2bf(p);
            h4[rg] = ph_;
            l4[rg] = f2bf(p - bf2f(ph_));
        }
        *reinterpret_cast<bf16x4*>(&Ph[key*16 + q*4]) = h4;
        *reinterpret_cast<bf16x4*>(&Pl[key*16 + q*4]) = l4;
    }

    // write prefetched V chunk 0
    #pragma unroll
    for (int i = 0; i < 4; ++i) {
        int tt = tid + 256*(i & 3);
        int key = (tt >> 3) & 63, jb = tt & 7, part = tt >> 9;
        short* dstp = (part ? Vl : Vh) + key*64 + (((jb*2) ^ ((key & 3) << 2)) * 4);
        *reinterpret_cast<bf16x8*>(dstp) = vreg[i];
    }
    __syncthreads();

    const unsigned phb = (unsigned)(size_t)&Ph[0];
    const unsigned plb = (unsigned)(size_t)&Pl[0];
    const unsigned vhb = (unsigned)(size_t)&Vh[0];
    const unsigned vlb = (unsigned)(size_t)&Vl[0];

    // ---- PV over 8 chunks of 64 keys ----
    f32x4 oacc = (f32x4){0.f, 0.f, 0.f, 0.f};
    #pragma unroll
    for (int c = 0; c < 8; ++c) {
        if (c < 7) {
            #pragma unroll
            for (int i = 0; i < 4; ++i) {
                int tt = tid + 256*(i & 3);
                int key = (tt >> 3) & 63, jb = tt & 7, part = tt >> 9;
                vreg[i] = *reinterpret_cast<const bf16x8*>(
                    Vhl + ((size_t)b*NS + idxs[(c+1)*64 + key])*128 + part*64 + jb*8);
            }
        }
        #pragma unroll
        for (int ks = 0; ks < 2; ++ks) {
            unsigned pa = phb + (unsigned)((c*64 + ks*32 + 8*q + (d15 >> 2))*32 + (d15 & 3)*8);
            unsigned pla = pa + (plb - phb);
            unsigned va = vhb + (unsigned)((ks*32 + 8*q + (d15 >> 2))*128
                                           + (((w*4 + (d15 & 3)) ^ ((d15 >> 2) << 2)) * 8));
            unsigned vla = va + (vlb - vhb);
            bf16x4 p0, p1, r0, r1, v0, v1, u0, u1;
            TR64(p0, pa,  "0");   TR64(p1, pa,  "128");
            TR64(r0, pla, "0");   TR64(r1, pla, "128");
            TR64(v0, va,  "0");   TR64(v1, va,  "512");
            TR64(u0, vla, "0");   TR64(u1, vla, "512");
            asm volatile("s_waitcnt lgkmcnt(0)" ::: "memory");
            __builtin_amdgcn_sched_barrier(0);
            bf16x8 pH = __builtin_shufflevector(p0, p1, 0,1,2,3,4,5,6,7);
            bf16x8 pL = __builtin_shufflevector(r0, r1, 0,1,2,3,4,5,6,7);
            bf16x8 vH = __builtin_shufflevector(v0, v1, 0,1,2,3,4,5,6,7);
            bf16x8 vL = __builtin_shufflevector(u0, u1, 0,1,2,3,4,5,6,7);
            oacc = __builtin_amdgcn_mfma_f32_16x16x32_bf16(pH, vH, oacc, 0, 0, 0);
            oacc = __builtin_amdgcn_mfma_f32_16x16x32_bf16(pL, vH, oacc, 0, 0, 0);
            oacc = __builtin_amdgcn_mfma_f32_16x16x32_bf16(pH, vL, oacc, 0, 0, 0);
        }
        if (c < 7) {
            __syncthreads();
            #pragma unroll
            for (int i = 0; i < 4; ++i) {
                int tt = tid + 256*(i & 3);
                int key = (tt >> 3) & 63, jb = tt & 7, part = tt >> 9;
                short* dstp = (part ? Vl : Vh) + key*64 + (((jb*2) ^ ((key & 3) << 2)) * 4);
                *reinterpret_cast<bf16x8*>(dstp) = vreg[i];
            }
            __syncthreads();
        }
    }

    #pragma unroll
    for (int rg = 0; rg < 4; ++rg) {
        int hh = q*4 + rg;
        out[((size_t)b*NS + s)*(NH*NDK) + hh*NDK + w*16 + d15] = oacc[rg];
    }
    if (blk == 0 && tid == 0) out[(size_t)NB*NS*NH*NDK] = 0.f;  // kl_loss
}

// ============================ launch =======================================
extern "C" void kernel_launch(void* const* d_in, const int* in_sizes, int n_in,
                              void* d_out, int out_size, void* d_ws, size_t ws_size,
                              hipStream_t stream) {
    const float* x     = (const float*)d_in[0];
    const float* Q     = (const float*)d_in[1];
    const float* K     = (const float*)d_in[2];
    const float* V     = (const float*)d_in[3];
    const float* Wq    = (const float*)d_in[4];
    const float* bq    = (const float*)d_in[5];
    const float* Wk    = (const float*)d_in[6];
    const float* bk    = (const float*)d_in[7];
    const float* gamma = (const float*)d_in[8];
    const float* beta  = (const float*)d_in[9];
    const float* hw    = (const float*)d_in[10];
    float* outp = (float*)d_out;

    // ws layout (44 MB):
    //   [0, 4.19M)     : q_index fp32  (top_idx aliased here after k2)
    //   [4.19, 8.39M)  : k_index fp32
    //   [8.39, 41.9M)  : keys u32
    //   [41.9, 42.9M)  : Khl bf16 hi/lo
    //   [42.9, 44.0M)  : Vhl bf16 hi/lo
    float* q_index = (float*)d_ws;
    float* k_index = q_index + (size_t)NB*NS*NHI*NDI;
    u32*   keys    = (u32*)(k_index + (size_t)NB*NS*NHI*NDI);
    short* Khl     = (short*)(keys + (size_t)NB*NS*NS);
    short* Vhl     = Khl + (size_t)NB*NS*128;
    int*   top_idx = (int*)d_ws;              // aliases q/k region (dead after k2)

    k0_split<<<(NB*NS*NDK)/256, 256, 0, stream>>>(K, V, Khl, Vhl);
    k1_proj_ln<<<(NB*NS/ROWS1)*2, 256, 0, stream>>>(x, Wq, bq, Wk, bk, gamma, beta, q_index, k_index);
    k2_scores<<<dim3(NS/128, NS/64, NB), 256, 0, stream>>>(q_index, k_index, hw, keys);
    k3_select<<<NB*NS, 256, 0, stream>>>(keys, top_idx);
    k4_attn_mfma<<<NB*NS, 256, 0, stream>>>(Q, Khl, Vhl, top_idx, outp);
}

// Round 2
// 486.061 us; speedup vs baseline: 1.4169x; 1.4169x over previous
//
#include <hip/hip_runtime.h>
#include <hip/hip_bf16.h>

#define NB 2
#define NS 2048
#define ND 1024
#define NH 16
#define NDK 64
#define NHI 4
#define NDI 64
#define NTOPK 512

typedef unsigned int u32;

typedef __attribute__((ext_vector_type(8))) short bf16x8;
typedef __attribute__((ext_vector_type(4))) short bf16x4;
typedef __attribute__((ext_vector_type(4))) float f32x4;

__device__ __forceinline__ short f2bf(float f) {
    u32 u = __float_as_uint(f);
    u += 0x7fffu + ((u >> 16) & 1u);   // round-to-nearest-even bf16
    return (short)(u >> 16);
}
__device__ __forceinline__ float bf2f(short h) {
    return __uint_as_float(((u32)(unsigned short)h) << 16);
}
__device__ __forceinline__ float4 fma4(float4 a, float4 b, float4 c) {
    float4 r;
    r.x = fmaf(a.x, b.x, c.x); r.y = fmaf(a.y, b.y, c.y);
    r.z = fmaf(a.z, b.z, c.z); r.w = fmaf(a.w, b.w, c.w);
    return r;
}
__device__ __forceinline__ float bcast_lane(float v, int k) {
    return __int_as_float(__builtin_amdgcn_readlane(__float_as_int(v), k));
}

#define TR64(dst, addr, OFF) \
    asm volatile("ds_read_b64_tr_b16 %0, %1 offset:" OFF : "=v"(dst) : "v"(addr))

// ============================ Kernel 0 =====================================
__global__ __launch_bounds__(256) void k0_split(
    const float* __restrict__ K, const float* __restrict__ V,
    short* __restrict__ Khl, short* __restrict__ Vhl)
{
    int e = blockIdx.x*256 + threadIdx.x;     // e < NB*NS*NDK
    int row = e >> 6, d = e & 63;
    float kf = K[e], vf = V[e];
    short kh = f2bf(kf), vh = f2bf(vf);
    short kl = f2bf(kf - bf2f(kh)), vl = f2bf(vf - bf2f(vh));
    Khl[(size_t)row*128 + d]      = kh;
    Khl[(size_t)row*128 + 64 + d] = kl;
    Vhl[(size_t)row*128 + d]      = vh;
    Vhl[(size_t)row*128 + 64 + d] = vl;
}

// ============================ Kernel 1 =====================================
// np-mimic: proj = x@W (OpenBLAS sequential-k FMA chains, kc=384 panels
// (P1+P2)+P3, +bias), then numpy-pairwise LayerNorm. BIT-EXACT chains.
// v2 (kept from r1, ~86us): x read via the SCALAR path (uniform global
// float4 loads -> s_load), LDS only the 8 KB proj buffer for LN.
#define ROWS1 8
__global__ __launch_bounds__(256) void k1_proj_ln(
    const float* __restrict__ x, const float* __restrict__ Wq, const float* __restrict__ bq,
    const float* __restrict__ Wk, const float* __restrict__ bk,
    const float* __restrict__ gamma, const float* __restrict__ beta,
    float* __restrict__ q_index, float* __restrict__ k_index)
{
    __shared__ float projf[ROWS1*256];              // 8 KB
    const int tid = threadIdx.x;
    const int m = blockIdx.x & 1;                   // 0 = Wq, 1 = Wk
    const int row0 = (blockIdx.x >> 1) * ROWS1;
    const float* __restrict__ W    = m ? Wk : Wq;
    const float* __restrict__ bias = m ? bk : bq;
    const int c = tid;
    const float4* __restrict__ xg =
        reinterpret_cast<const float4*>(x) + (size_t)row0 * (ND/4);

    float acc[ROWS1];
    const int panel_lo4[3] = {0, 96, 192};
    const int panel_hi4[3] = {96, 192, 256};
    #pragma unroll
    for (int p = 0; p < 3; ++p) {
        float P[ROWS1];
        #pragma unroll
        for (int r = 0; r < ROWS1; ++r) P[r] = 0.f;
        for (int k4 = panel_lo4[p]; k4 < panel_hi4[p]; ++k4) {
            float4 xv[ROWS1];
            #pragma unroll
            for (int r = 0; r < ROWS1; ++r)
                xv[r] = xg[r*256 + k4];             // uniform addr -> s_load
            #pragma unroll
            for (int kk = 0; kk < 4; ++kk) {
                float wv = W[(size_t)(k4*4 + kk)*256 + c];
                #pragma unroll
                for (int r = 0; r < ROWS1; ++r) {
                    float xs_ = (kk == 0) ? xv[r].x : (kk == 1) ? xv[r].y : (kk == 2) ? xv[r].z : xv[r].w;
                    P[r] = fmaf(xs_, wv, P[r]);
                }
            }
        }
        #pragma unroll
        for (int r = 0; r < ROWS1; ++r) {
            if (p == 0) acc[r] = P[r];
            else        acc[r] = acc[r] + P[r];
        }
    }
    float bv = bias[c];
    #pragma unroll
    for (int r = 0; r < ROWS1; ++r) projf[r*256 + c] = acc[r] + bv;
    __syncthreads();

    // numpy-pairwise LayerNorm (8-accumulator pattern, n=64); 4 heads here
    if (tid < ROWS1*4) {
        const int r = tid >> 2, hd = tid & 3;
        const float* pp = &projf[r*256 + hd*64];
        float rr[8];
        #pragma unroll
        for (int q8 = 0; q8 < 8; ++q8) rr[q8] = pp[q8];
        #pragma unroll
        for (int i = 8; i < 64; i += 8)
            #pragma unroll
            for (int q8 = 0; q8 < 8; ++q8) rr[q8] += pp[i + q8];
        float ssum = ((rr[0]+rr[1]) + (rr[2]+rr[3])) + ((rr[4]+rr[5]) + (rr[6]+rr[7]));
        float mu = ssum / 64.0f;

        #pragma unroll
        for (int q8 = 0; q8 < 8; ++q8) { float dv = pp[q8] - mu; rr[q8] = dv*dv; }
        #pragma unroll
        for (int i = 8; i < 64; i += 8)
            #pragma unroll
            for (int q8 = 0; q8 < 8; ++q8) { float dv = pp[i+q8] - mu; rr[q8] += dv*dv; }
        float vsum = ((rr[0]+rr[1]) + (rr[2]+rr[3])) + ((rr[4]+rr[5]) + (rr[6]+rr[7]));
        float var = vsum / 64.0f;
        float inv = 1.0f / (float)sqrt((double)(var + 1e-5f));

        float* dst = (m ? k_index : q_index)
                     + ((size_t)(row0 + r)) * (NHI*NDI) + hd*64;
        for (int i = 0; i < 64; ++i) {
            float dv = pp[i] - mu;
            float t = dv * inv;
            t = t * gamma[i];
            t = t + beta[i];
            dst[i] = t;
        }
    }
}

// ============================ Kernel 2 =====================================
// np-mimic fp32 scores (npyv-AVX512 contig_two emulation). BIT-EXACT path.
// v3: r11-proven LDS staging structure, but the A-row consumption is changed
// from 16x wave-uniform ds_read_b128 broadcasts per row (192 LDS-pipe cyc,
// 6x oversubscribed vs 4 SIMDs) to ONE conflict-free ds_read_b32 per lane
// (A[row][lane]) + v_readlane broadcasts on the VALU pipe feeding
// v_fmac(v,s,v). Accumulation order per scalar slot and the l0..l3 tree
// are preserved verbatim -> bit-exact.
__global__ __launch_bounds__(256) void k2_scores(
    const float* __restrict__ q_index, const float* __restrict__ k_index,
    const float* __restrict__ hw, u32* __restrict__ keys)
{
    __shared__ float As[64*64];   // 16 KB
    __shared__ float Bs[64*64];   // 16 KB
    const int tid = threadIdx.x;
    const int t0 = blockIdx.x * 64, s0 = blockIdx.y * 64, b = blockIdx.z;
    const int lane = tid & 63;
    const int wv = tid >> 6;

    float fin[16];
    #pragma unroll
    for (int r = 0; r < 16; ++r) fin[r] = 0.f;

    for (int h = 0; h < NHI; ++h) {
        __syncthreads();
        #pragma unroll
        for (int i = 0; i < 8; ++i) {
            int e = tid + 256*i;
            int side = e >> 10;
            int row = (e >> 4) & 63;
            int q4 = e & 15;
            const float* src = (side ? q_index : k_index)
                + (((size_t)b*NS + (side ? t0 : s0) + row)*NHI + h)*NDI + q4*4;
            float4 v = *reinterpret_cast<const float4*>(src);
            float* dstp = (side ? Bs : As) + row*64 + ((q4 ^ (row & 15)) * 4);
            *reinterpret_cast<float4*>(dstp) = v;
        }
        __syncthreads();

        float4 bf[16];
        #pragma unroll
        for (int q4 = 0; q4 < 16; ++q4)
            bf[q4] = *reinterpret_cast<const float4*>(&Bs[lane*64 + ((q4 ^ (lane & 15)) * 4)]);

        float w = hw[h];
        #pragma unroll
        for (int r = 0; r < 16; ++r) {
            const int row = wv*16 + r;
            const int f = row & 15;
            // one b32 per lane: av(lane) = A[row][lane] (unswizzle XOR layout)
            float av = As[row*64 + ((((lane >> 2) ^ f) << 2) | (lane & 3))];
            // acc16[i*4+m] corresponds to l_i component m of the npyv chain
            float acc16[16];
            #pragma unroll
            for (int j = 0; j < 16; ++j) acc16[j] = 0.f;
            #pragma unroll
            for (int c = 0; c < 4; ++c) {
                #pragma unroll
                for (int i = 0; i < 4; ++i) {
                    float bx = bf[c*4+i].x, by = bf[c*4+i].y,
                          bz = bf[c*4+i].z, bw = bf[c*4+i].w;
                    int kbase = c*16 + i*4;
                    acc16[i*4+0] = fmaf(bcast_lane(av, kbase+0), bx, acc16[i*4+0]);
                    acc16[i*4+1] = fmaf(bcast_lane(av, kbase+1), by, acc16[i*4+1]);
                    acc16[i*4+2] = fmaf(bcast_lane(av, kbase+2), bz, acc16[i*4+2]);
                    acc16[i*4+3] = fmaf(bcast_lane(av, kbase+3), bw, acc16[i*4+3]);
                }
            }
            // reduction tree identical to npyv emulation:
            // u = l0+l2, v2 = l1+l3, t2 = u+v2, dot = (t2.x+t2.z)+(t2.y+t2.w)
            float u0 = acc16[0]  + acc16[8];
            float u1 = acc16[1]  + acc16[9];
            float u2 = acc16[2]  + acc16[10];
            float u3 = acc16[3]  + acc16[11];
            float v0 = acc16[4]  + acc16[12];
            float v1 = acc16[5]  + acc16[13];
            float v2_ = acc16[6] + acc16[14];
            float v3 = acc16[7]  + acc16[15];
            float tx = u0 + v0, ty = u1 + v1, tz = u2 + v2_, tw = u3 + v3;
            float s3a = tx + tz, s3b = ty + tw;
            float dot = s3a + s3b;
            fin[r] = fmaf(w, fmaxf(dot, 0.f), fin[r]);
        }
    }
    #pragma unroll
    for (int r = 0; r < 16; ++r)
        keys[((size_t)b*NS + s0 + wv*16 + r)*NS + t0 + lane] = __float_as_uint(fin[r]);
}

// ============================ Kernel 3 =====================================
// Exact top-512 per row via 4x8-bit radix select on u32 keys (fp32 bits).
// Scans done by WAVE 0 only (in-lane 4-elem suffix/prefix + 6 shfl steps,
// u32-exact, identical outputs) -> ~20 barriers/block instead of ~90.
__global__ __launch_bounds__(256) void k3_select(
    const u32* __restrict__ keys_g, int* __restrict__ top_idx)
{
    __shared__ u32 hist[256];
    __shared__ u32 scan[256];
    __shared__ u32 sel_byte, sel_above;
    const int tid = threadIdx.x;
    const size_t row = blockIdx.x;
    const u32* src = keys_g + row * NS;

    u32 keys[8];
    #pragma unroll
    for (int i = 0; i < 8; ++i) keys[i] = src[tid*8 + i];

    u32 prefix = 0, kk = NTOPK, total_gt = 0;
    #pragma unroll
    for (int pass = 0; pass < 4; ++pass) {
        const int shift = 24 - pass*8;
        const u32 mask_hi = (pass == 0) ? 0u : (0xFFFFFFFFu << (shift + 8));
        hist[tid] = 0;
        __syncthreads();
        #pragma unroll
        for (int i = 0; i < 8; ++i)
            if (((keys[i] ^ prefix) & mask_hi) == 0u)
                atomicAdd(&hist[(keys[i] >> shift) & 255], 1u);
        __syncthreads();
        // inclusive suffix scan over 256 bins, by wave 0 only
        if (tid < 64) {
            u32 v0 = hist[tid*4+0], v1 = hist[tid*4+1], v2 = hist[tid*4+2], v3 = hist[tid*4+3];
            u32 s3 = v3, s2 = v2 + s3, s1 = v1 + s2, s0 = v0 + s1;
            u32 suf = s0;
            #pragma unroll
            for (int o = 1; o < 64; o <<= 1) {
                u32 t = __shfl_down(suf, o, 64);
                if (tid + o < 64) suf += t;
            }
            u32 excl = suf - s0;   // sum over lanes > tid (u32-exact)
            hist[tid*4+0] = s0 + excl;
            hist[tid*4+1] = s1 + excl;
            hist[tid*4+2] = s2 + excl;
            hist[tid*4+3] = s3 + excl;
        }
        __syncthreads();
        if (hist[tid] >= kk && (tid == 255 || hist[tid+1] < kk)) {
            sel_byte = (u32)tid;
            sel_above = (tid == 255) ? 0u : hist[tid+1];
        }
        __syncthreads();
        u32 sb = sel_byte, sa = sel_above;
        prefix |= (sb << shift);
        total_gt += sa;
        kk -= sa;
    }

    const u32 T = prefix;
    const u32 needed = NTOPK - total_gt;

    u32 cgt = 0, ceq = 0;
    #pragma unroll
    for (int i = 0; i < 8; ++i) { cgt += (keys[i] > T); ceq += (keys[i] == T); }
    scan[tid] = (cgt << 16) | ceq;
    __syncthreads();
    // inclusive prefix scan over 256 threads, by wave 0 only
    if (tid < 64) {
        u32 v0 = scan[tid*4+0], v1 = scan[tid*4+1], v2 = scan[tid*4+2], v3 = scan[tid*4+3];
        u32 p0 = v0, p1 = p0 + v1, p2 = p1 + v2, p3 = p2 + v3;
        u32 pre = p3;
        #pragma unroll
        for (int o = 1; o < 64; o <<= 1) {
            u32 t = __shfl_up(pre, o, 64);
            if (tid >= o) pre += t;
        }
        u32 excl = pre - p3;   // sum over lanes < tid
        scan[tid*4+0] = p0 + excl;
        scan[tid*4+1] = p1 + excl;
        scan[tid*4+2] = p2 + excl;
        scan[tid*4+3] = p3 + excl;
    }
    __syncthreads();
    u32 incl = scan[tid];
    u32 gt_pref = (incl >> 16) - cgt;
    u32 eq_pref = (incl & 0xFFFFu) - ceq;

    int* dst = top_idx + row * NTOPK;
    u32 lgt = 0, leq = 0;
    #pragma unroll
    for (int i = 0; i < 8; ++i) {
        int idx = tid*8 + i;
        if (keys[i] > T) {
            u32 eqsel = eq_pref + leq; if (eqsel > needed) eqsel = needed;
            u32 slot = gt_pref + lgt + eqsel;
            if (slot < NTOPK) dst[slot] = idx;
            lgt++;
        } else if (keys[i] == T) {
            u32 er = eq_pref + leq;
            if (er < needed) {
                u32 slot = gt_pref + lgt + er;
                if (slot < NTOPK) dst[slot] = idx;
            }
            leq++;
        }
    }
}

// ============================ Kernel 4 =====================================
// Gathered attention, split-bf16 3-term MFMA, precomputed Khl/Vhl.
__global__ __launch_bounds__(256) void k4_attn_mfma(
    const float* __restrict__ Qg, const short* __restrict__ Khl, const short* __restrict__ Vhl,
    const int* __restrict__ top_idx, float* __restrict__ out)
{
    __shared__ short Ph[NTOPK*16];  // P^T hi [key][head] 16 KB
    __shared__ short Pl[NTOPK*16];  // 16 KB
    __shared__ short Vh[64*64];     // V chunk, subtiled-swizzled, 8 KB
    __shared__ short Vl[64*64];     // 8 KB
    __shared__ float red[2][16][4];
    __shared__ int   idxs[NTOPK];

    const int tid = threadIdx.x;
    const int l = tid & 63, w = tid >> 6;
    const int q = l >> 4, d15 = l & 15;
    const size_t blk = blockIdx.x;
    const int b = (int)(blk >> 11), s = (int)(blk & 2047);

    for (int i = tid; i < NTOPK; i += 256) idxs[i] = top_idx[blk*NTOPK + i];

    // Q A-fragments: row(head)=d15, k = ks*32 + q*8 + j
    bf16x8 qhi[2], qlo[2];
    {
        const float* qp = Qg + (((size_t)b*NH + d15)*NS + s)*NDK + q*8;
        #pragma unroll
        for (int ks = 0; ks < 2; ++ks) {
            float4 f0 = *reinterpret_cast<const float4*>(qp + ks*32);
            float4 f1 = *reinterpret_cast<const float4*>(qp + ks*32 + 4);
            float fv[8] = {f0.x,f0.y,f0.z,f0.w,f1.x,f1.y,f1.z,f1.w};
            #pragma unroll
            for (int jj = 0; jj < 8; ++jj) {
                short hh = f2bf(fv[jj]);
                qhi[ks][jj] = hh;
                qlo[ks][jj] = f2bf(fv[jj] - bf2f(hh));
            }
        }
    }
    __syncthreads();   // idxs ready

    f32x4 sacc[8];
    #pragma unroll
    for (int t = 0; t < 8; ++t) sacc[t] = (f32x4){0.f, 0.f, 0.f, 0.f};

    // ---- QK^T: direct global gather of K fragments ----
    #pragma unroll
    for (int c = 0; c < 4; ++c) {
        #pragma unroll
        for (int t = 0; t < 2; ++t) {
            int key = c*128 + w*32 + t*16 + d15;
            int kidx = idxs[key];
            const short* rowp = Khl + ((size_t)b*NS + kidx)*128;
            int ti = c*2 + t;
            #pragma unroll
            for (int ks = 0; ks < 2; ++ks) {
                bf16x8 kh = *reinterpret_cast<const bf16x8*>(rowp + ks*32 + q*8);
                bf16x8 kl = *reinterpret_cast<const bf16x8*>(rowp + 64 + ks*32 + q*8);
                sacc[ti] = __builtin_amdgcn_mfma_f32_16x16x32_bf16(qhi[ks], kh, sacc[ti], 0, 0, 0);
                sacc[ti] = __builtin_amdgcn_mfma_f32_16x16x32_bf16(qlo[ks], kh, sacc[ti], 0, 0, 0);
                sacc[ti] = __builtin_amdgcn_mfma_f32_16x16x32_bf16(qhi[ks], kl, sacc[ti], 0, 0, 0);
            }
        }
    }

    // ---- prefetch V chunk 0 into regs ----
    bf16x8 vreg[4];
    #pragma unroll
    for (int i = 0; i < 4; ++i) {
        int tt = tid + 256*(i & 3);
        int key = (tt >> 3) & 63, jb = tt & 7, part = tt >> 9;
        vreg[i] = *reinterpret_cast<const bf16x8*>(
            Vhl + ((size_t)b*NS + idxs[0*64 + key])*128 + part*64 + jb*8);
    }

    // ---- softmax: head = q*4 + rg, distributed over 4 waves ----
    float m[4], inv[4];
    #pragma unroll
    for (int rg = 0; rg < 4; ++rg) {
        float mm = -3.4e38f;
        #pragma unroll
        for (int t = 0; t < 8; ++t) { sacc[t][rg] *= 0.125f; mm = fmaxf(mm, sacc[t][rg]); }
        #pragma unroll
        for (int o = 1; o <= 8; o <<= 1) mm = fmaxf(mm, __shfl_xor(mm, o));
        m[rg] = mm;
    }
    if (d15 == 0) {
        #pragma unroll
        for (int rg = 0; rg < 4; ++rg) red[0][q*4 + rg][w] = m[rg];
    }
    __syncthreads();
    float sum[4];
    #pragma unroll
    for (int rg = 0; rg < 4; ++rg) {
        int hh = q*4 + rg;
        float g = fmaxf(fmaxf(red[0][hh][0], red[0][hh][1]),
                        fmaxf(red[0][hh][2], red[0][hh][3]));
        float ss = 0.f;
        #pragma unroll
        for (int t = 0; t < 8; ++t) { float p = __expf(sacc[t][rg] - g); sacc[t][rg] = p; ss += p; }
        #pragma unroll
        for (int o = 1; o <= 8; o <<= 1) ss += __shfl_xor(ss, o);
        sum[rg] = ss;
    }
    if (d15 == 0) {
        #pragma unroll
        for (int rg = 0; rg < 4; ++rg) red[1][q*4 + rg][w] = sum[rg];
    }
    __syncthreads();
    #pragma unroll
    for (int rg = 0; rg < 4; ++rg) {
        int hh = q*4 + rg;
        inv[rg] = 1.f / (red[1][hh][0] + red[1][hh][1] + red[1][hh][2] + red[1][hh][3]);
    }

    // ---- write P transposed [key][16 heads], split bf16, b64 writes ----
    #pragma unroll
    for (int t = 0; t < 8; ++t) {
        int key = (t >> 1)*128 + w*32 + (t & 1)*16 + d15;
        bf16x4 h4, l4;
        #pragma unroll
        for (int rg = 0; rg < 4; ++rg) {
            float p = sacc[t][rg] * inv[rg];
            short ph_ = f2bf(p);
            h4[rg] = ph_;
            l4[rg] = f2bf(p - bf2f(ph_));
        }
        *reinterpret_cast<bf16x4*>(&Ph[key*16 + q*4]) = h4;
        *reinterpret_cast<bf16x4*>(&Pl[key*16 + q*4]) = l4;
    }

    // write prefetched V chunk 0
    #pragma unroll
    for (int i = 0; i < 4; ++i) {
        int tt = tid + 256*(i & 3);
        int key = (tt >> 3) & 63, jb = tt & 7, part = tt >> 9;
        short* dstp = (part ? Vl : Vh) + key*64 + (((jb*2) ^ ((key & 3) << 2)) * 4);
        *reinterpret_cast<bf16x8*>(dstp) = vreg[i];
    }
    __syncthreads();

    const unsigned phb = (unsigned)(size_t)&Ph[0];
    const unsigned plb = (unsigned)(size_t)&Pl[0];
    const unsigned vhb = (unsigned)(size_t)&Vh[0];
    const unsigned vlb = (unsigned)(size_t)&Vl[0];

    // ---- PV over 8 chunks of 64 keys ----
    f32x4 oacc = (f32x4){0.f, 0.f, 0.f, 0.f};
    #pragma unroll
    for (int c = 0; c < 8; ++c) {
        if (c < 7) {
            #pragma unroll
            for (int i = 0; i < 4; ++i) {
                int tt = tid + 256*(i & 3);
                int key = (tt >> 3) & 63, jb = tt & 7, part = tt >> 9;
                vreg[i] = *reinterpret_cast<const bf16x8*>(
                    Vhl + ((size_t)b*NS + idxs[(c+1)*64 + key])*128 + part*64 + jb*8);
            }
        }
        #pragma unroll
        for (int ks = 0; ks < 2; ++ks) {
            unsigned pa = phb + (unsigned)((c*64 + ks*32 + 8*q + (d15 >> 2))*32 + (d15 & 3)*8);
            unsigned pla = pa + (plb - phb);
            unsigned va = vhb + (unsigned)((ks*32 + 8*q + (d15 >> 2))*128
                                           + (((w*4 + (d15 & 3)) ^ ((d15 >> 2) << 2)) * 8));
            unsigned vla = va + (vlb - vhb);
            bf16x4 p0, p1, r0, r1, v0, v1, u0, u1;
            TR64(p0, pa,  "0");   TR64(p1, pa,  "128");
            TR64(r0, pla, "0");   TR64(r1, pla, "128");
            TR64(v0, va,  "0");   TR64(v1, va,  "512");
            TR64(u0, vla, "0");   TR64(u1, vla, "512");
            asm volatile("s_waitcnt lgkmcnt(0)" ::: "memory");
            __builtin_amdgcn_sched_barrier(0);
            bf16x8 pH = __builtin_shufflevector(p0, p1, 0,1,2,3,4,5,6,7);
            bf16x8 pL = __builtin_shufflevector(r0, r1, 0,1,2,3,4,5,6,7);
            bf16x8 vH = __builtin_shufflevector(v0, v1, 0,1,2,3,4,5,6,7);
            bf16x8 vL = __builtin_shufflevector(u0, u1, 0,1,2,3,4,5,6,7);
            oacc = __builtin_amdgcn_mfma_f32_16x16x32_bf16(pH, vH, oacc, 0, 0, 0);
            oacc = __builtin_amdgcn_mfma_f32_16x16x32_bf16(pL, vH, oacc, 0, 0, 0);
            oacc = __builtin_amdgcn_mfma_f32_16x16x32_bf16(pH, vL, oacc, 0, 0, 0);
        }
        if (c < 7) {
            __syncthreads();
            #pragma unroll
            for (int i = 0; i < 4; ++i) {
                int tt = tid + 256*(i & 3);
                int key = (tt >> 3) & 63, jb = tt & 7, part = tt >> 9;
                short* dstp = (part ? Vl : Vh) + key*64 + (((jb*2) ^ ((key & 3) << 2)) * 4);
                *reinterpret_cast<bf16x8*>(dstp) = vreg[i];
            }
            __syncthreads();
        }
    }

    #pragma unroll
    for (int rg = 0; rg < 4; ++rg) {
        int hh = q*4 + rg;
        out[((size_t)b*NS + s)*(NH*NDK) + hh*NDK + w*16 + d15] = oacc[rg];
    }
    if (blk == 0 && tid == 0) out[(size_t)NB*NS*NH*NDK] = 0.f;  // kl_loss
}

// ============================ launch =======================================
extern "C" void kernel_launch(void* const* d_in, const int* in_sizes, int n_in,
                              void* d_out, int out_size, void* d_ws, size_t ws_size,
                              hipStream_t stream) {
    const float* x     = (const float*)d_in[0];
    const float* Q     = (const float*)d_in[1];
    const float* K     = (const float*)d_in[2];
    const float* V     = (const float*)d_in[3];
    const float* Wq    = (const float*)d_in[4];
    const float* bq    = (const float*)d_in[5];
    const float* Wk    = (const float*)d_in[6];
    const float* bk    = (const float*)d_in[7];
    const float* gamma = (const float*)d_in[8];
    const float* beta  = (const float*)d_in[9];
    const float* hw    = (const float*)d_in[10];
    float* outp = (float*)d_out;

    // ws layout (44 MB):
    //   [0, 4.19M)     : q_index fp32  (top_idx aliased here after k2)
    //   [4.19, 8.39M)  : k_index fp32
    //   [8.39, 41.9M)  : keys u32
    //   [41.9, 42.9M)  : Khl bf16 hi/lo
    //   [42.9, 44.0M)  : Vhl bf16 hi/lo
    float* q_index = (float*)d_ws;
    float* k_index = q_index + (size_t)NB*NS*NHI*NDI;
    u32*   keys    = (u32*)(k_index + (size_t)NB*NS*NHI*NDI);
    short* Khl     = (short*)(keys + (size_t)NB*NS*NS);
    short* Vhl     = Khl + (size_t)NB*NS*128;
    int*   top_idx = (int*)d_ws;              // aliases q/k region (dead after k2)

    k0_split<<<(NB*NS*NDK)/256, 256, 0, stream>>>(K, V, Khl, Vhl);
    k1_proj_ln<<<(NB*NS/ROWS1)*2, 256, 0, stream>>>(x, Wq, bq, Wk, bk, gamma, beta, q_index, k_index);
    k2_scores<<<dim3(NS/64, NS/64, NB), 256, 0, stream>>>(q_index, k_index, hw, keys);
    k3_select<<<NB*NS, 256, 0, stream>>>(keys, top_idx);
    k4_attn_mfma<<<NB*NS, 256, 0, stream>>>(Q, Khl, Vhl, top_idx, outp);
}

// Round 3
// 314.932 us; speedup vs baseline: 2.1868x; 1.5434x over previous
//
#include <hip/hip_runtime.h>
#include <hip/hip_bf16.h>

#define NB 2
#define NS 2048
#define ND 1024
#define NH 16
#define NDK 64
#define NHI 4
#define NDI 64
#define NTOPK 512

typedef unsigned int u32;

typedef __attribute__((ext_vector_type(8))) short bf16x8;
typedef __attribute__((ext_vector_type(4))) short bf16x4;
typedef __attribute__((ext_vector_type(4))) float f32x4;
typedef __attribute__((ext_vector_type(16))) float f32x16;

__device__ __forceinline__ short f2bf(float f) {
    u32 u = __float_as_uint(f);
    u += 0x7fffu + ((u >> 16) & 1u);   // round-to-nearest-even bf16
    return (short)(u >> 16);
}
__device__ __forceinline__ float bf2f(short h) {
    return __uint_as_float(((u32)(unsigned short)h) << 16);
}

#define TR64(dst, addr, OFF) \
    asm volatile("ds_read_b64_tr_b16 %0, %1 offset:" OFF : "=v"(dst) : "v"(addr))

// ============================ Kernel 0 =====================================
__global__ __launch_bounds__(256) void k0_split(
    const float* __restrict__ K, const float* __restrict__ V,
    short* __restrict__ Khl, short* __restrict__ Vhl)
{
    int e = blockIdx.x*256 + threadIdx.x;     // e < NB*NS*NDK
    int row = e >> 6, d = e & 63;
    float kf = K[e], vf = V[e];
    short kh = f2bf(kf), vh = f2bf(vf);
    short kl = f2bf(kf - bf2f(kh)), vl = f2bf(vf - bf2f(vh));
    Khl[(size_t)row*128 + d]      = kh;
    Khl[(size_t)row*128 + 64 + d] = kl;
    Vhl[(size_t)row*128 + d]      = vh;
    Vhl[(size_t)row*128 + 64 + d] = vl;
}

// ============================ Kernel 1 =====================================
// np-mimic: proj = x@W (OpenBLAS sequential-k FMA chains, kc=384 panels
// (P1+P2)+P3, +bias), then numpy-pairwise LayerNorm. BIT-EXACT chains.
// v2 (kept from r1, ~86us): x read via the SCALAR path (uniform global
// float4 loads -> s_load), LDS only the 8 KB proj buffer for LN.
#define ROWS1 8
__global__ __launch_bounds__(256) void k1_proj_ln(
    const float* __restrict__ x, const float* __restrict__ Wq, const float* __restrict__ bq,
    const float* __restrict__ Wk, const float* __restrict__ bk,
    const float* __restrict__ gamma, const float* __restrict__ beta,
    float* __restrict__ q_index, float* __restrict__ k_index)
{
    __shared__ float projf[ROWS1*256];              // 8 KB
    const int tid = threadIdx.x;
    const int m = blockIdx.x & 1;                   // 0 = Wq, 1 = Wk
    const int row0 = (blockIdx.x >> 1) * ROWS1;
    const float* __restrict__ W    = m ? Wk : Wq;
    const float* __restrict__ bias = m ? bk : bq;
    const int c = tid;
    const float4* __restrict__ xg =
        reinterpret_cast<const float4*>(x) + (size_t)row0 * (ND/4);

    float acc[ROWS1];
    const int panel_lo4[3] = {0, 96, 192};
    const int panel_hi4[3] = {96, 192, 256};
    #pragma unroll
    for (int p = 0; p < 3; ++p) {
        float P[ROWS1];
        #pragma unroll
        for (int r = 0; r < ROWS1; ++r) P[r] = 0.f;
        for (int k4 = panel_lo4[p]; k4 < panel_hi4[p]; ++k4) {
            float4 xv[ROWS1];
            #pragma unroll
            for (int r = 0; r < ROWS1; ++r)
                xv[r] = xg[r*256 + k4];             // uniform addr -> s_load
            #pragma unroll
            for (int kk = 0; kk < 4; ++kk) {
                float wv = W[(size_t)(k4*4 + kk)*256 + c];
                #pragma unroll
                for (int r = 0; r < ROWS1; ++r) {
                    float xs_ = (kk == 0) ? xv[r].x : (kk == 1) ? xv[r].y : (kk == 2) ? xv[r].z : xv[r].w;
                    P[r] = fmaf(xs_, wv, P[r]);
                }
            }
        }
        #pragma unroll
        for (int r = 0; r < ROWS1; ++r) {
            if (p == 0) acc[r] = P[r];
            else        acc[r] = acc[r] + P[r];
        }
    }
    float bv = bias[c];
    #pragma unroll
    for (int r = 0; r < ROWS1; ++r) projf[r*256 + c] = acc[r] + bv;
    __syncthreads();

    // numpy-pairwise LayerNorm (8-accumulator pattern, n=64); 4 heads here
    if (tid < ROWS1*4) {
        const int r = tid >> 2, hd = tid & 3;
        const float* pp = &projf[r*256 + hd*64];
        float rr[8];
        #pragma unroll
        for (int q8 = 0; q8 < 8; ++q8) rr[q8] = pp[q8];
        #pragma unroll
        for (int i = 8; i < 64; i += 8)
            #pragma unroll
            for (int q8 = 0; q8 < 8; ++q8) rr[q8] += pp[i + q8];
        float ssum = ((rr[0]+rr[1]) + (rr[2]+rr[3])) + ((rr[4]+rr[5]) + (rr[6]+rr[7]));
        float mu = ssum / 64.0f;

        #pragma unroll
        for (int q8 = 0; q8 < 8; ++q8) { float dv = pp[q8] - mu; rr[q8] = dv*dv; }
        #pragma unroll
        for (int i = 8; i < 64; i += 8)
            #pragma unroll
            for (int q8 = 0; q8 < 8; ++q8) { float dv = pp[i+q8] - mu; rr[q8] += dv*dv; }
        float vsum = ((rr[0]+rr[1]) + (rr[2]+rr[3])) + ((rr[4]+rr[5]) + (rr[6]+rr[7]));
        float var = vsum / 64.0f;
        float inv = 1.0f / (float)sqrt((double)(var + 1e-5f));

        float* dst = (m ? k_index : q_index)
                     + ((size_t)(row0 + r)) * (NHI*NDI) + hd*64;
        for (int i = 0; i < 64; ++i) {
            float dv = pp[i] - mu;
            float t = dv * inv;
            t = t * gamma[i];
            t = t + beta[i];
            dst[i] = t;
        }
    }
}

// ============================ Kernel 2 =====================================
// np-mimic fp32 scores (npyv-AVX512 contig_two emulation). BIT-EXACT path.
// v4: B (q_index) staged in 16 KB LDS exactly as the proven r0 kernel.
// A (k_index) rows are wave-uniform -> read via the SCALAR MEMORY pipe
// (inline-asm s_load_dwordx16 into SGPR tuples, forced uniform via
// readfirstlane). FMAs consume SGPR operands directly (v_fmac v,s,v):
// zero extra VALU instrs, zero LDS traffic for A, SMEM pipe otherwise idle.
// Chain order identical to the npyv emulation -> bit-exact through top-k.
__global__ __launch_bounds__(256) void k2_scores(
    const float* __restrict__ q_index, const float* __restrict__ k_index,
    const float* __restrict__ hw, u32* __restrict__ keys)
{
    __shared__ float Bs[64*64];   // 16 KB
    const int tid = threadIdx.x;
    const int t0 = blockIdx.x * 64, s0 = blockIdx.y * 64, b = blockIdx.z;
    const int lane = tid & 63;
    const int wv = tid >> 6;

    float fin[16];
    #pragma unroll
    for (int r = 0; r < 16; ++r) fin[r] = 0.f;

    for (int h = 0; h < NHI; ++h) {
        __syncthreads();
        #pragma unroll
        for (int i = 0; i < 4; ++i) {
            int e = tid + 256*i;          // e < 1024
            int row = e >> 4;             // 0..63 (t-col)
            int q4 = e & 15;
            const float* src = q_index
                + (((size_t)b*NS + t0 + row)*NHI + h)*NDI + q4*4;
            float4 v = *reinterpret_cast<const float4*>(src);
            float* dstp = Bs + row*64 + ((q4 ^ (row & 15)) * 4);
            *reinterpret_cast<float4*>(dstp) = v;
        }
        __syncthreads();

        float4 bf[16];
        #pragma unroll
        for (int q4 = 0; q4 < 16; ++q4)
            bf[q4] = *reinterpret_cast<const float4*>(&Bs[lane*64 + ((q4 ^ (lane & 15)) * 4)]);

        float w = hw[h];
        #pragma unroll
        for (int r = 0; r < 16; ++r) {
            const int row = wv*16 + r;
            // byte offset of A row (k_index) -- wave-uniform by construction
            u32 off = (u32)((((u32)b*NS + (u32)(s0 + row))*NHI + (u32)h)*NDI*4u);
            off = __builtin_amdgcn_readfirstlane(off);
            const char* abase = reinterpret_cast<const char*>(k_index) + off;
            f32x16 A0, A1, A2, A3;
            asm volatile("s_load_dwordx16 %0, %1, 0x00" : "=s"(A0) : "s"(abase));
            asm volatile("s_load_dwordx16 %0, %1, 0x40" : "=s"(A1) : "s"(abase));
            asm volatile("s_load_dwordx16 %0, %1, 0x80" : "=s"(A2) : "s"(abase));
            asm volatile("s_load_dwordx16 %0, %1, 0xc0" : "=s"(A3) : "s"(abase));
            asm volatile("s_waitcnt lgkmcnt(0)" ::: "memory");
            __builtin_amdgcn_sched_barrier(0);

            // acc16[i*4+m] == l_i component m of the npyv chain
            float acc16[16];
            #pragma unroll
            for (int j = 0; j < 16; ++j) acc16[j] = 0.f;
            #pragma unroll
            for (int c = 0; c < 4; ++c) {
                const f32x16 A = (c == 0) ? A0 : (c == 1) ? A1 : (c == 2) ? A2 : A3;
                #pragma unroll
                for (int i = 0; i < 4; ++i) {
                    float bx = bf[c*4+i].x, by = bf[c*4+i].y,
                          bz = bf[c*4+i].z, bw = bf[c*4+i].w;
                    acc16[i*4+0] = fmaf(A[i*4+0], bx, acc16[i*4+0]);
                    acc16[i*4+1] = fmaf(A[i*4+1], by, acc16[i*4+1]);
                    acc16[i*4+2] = fmaf(A[i*4+2], bz, acc16[i*4+2]);
                    acc16[i*4+3] = fmaf(A[i*4+3], bw, acc16[i*4+3]);
                }
            }
            // reduction tree identical to npyv emulation:
            // u = l0+l2, v2 = l1+l3, t2 = u+v2, dot = (t2.x+t2.z)+(t2.y+t2.w)
            float u0 = acc16[0]  + acc16[8];
            float u1 = acc16[1]  + acc16[9];
            float u2 = acc16[2]  + acc16[10];
            float u3 = acc16[3]  + acc16[11];
            float v0 = acc16[4]  + acc16[12];
            float v1 = acc16[5]  + acc16[13];
            float v2_ = acc16[6] + acc16[14];
            float v3 = acc16[7]  + acc16[15];
            float tx = u0 + v0, ty = u1 + v1, tz = u2 + v2_, tw = u3 + v3;
            float s3a = tx + tz, s3b = ty + tw;
            float dot = s3a + s3b;
            fin[r] = fmaf(w, fmaxf(dot, 0.f), fin[r]);
        }
    }
    #pragma unroll
    for (int r = 0; r < 16; ++r)
        keys[((size_t)b*NS + s0 + wv*16 + r)*NS + t0 + lane] = __float_as_uint(fin[r]);
}

// ============================ Kernel 3 =====================================
// Exact top-512 per row via 4x8-bit radix select on u32 keys (fp32 bits).
// Scans done by WAVE 0 only (in-lane 4-elem suffix/prefix + 6 shfl steps,
// u32-exact, identical outputs) -> ~20 barriers/block instead of ~90.
__global__ __launch_bounds__(256) void k3_select(
    const u32* __restrict__ keys_g, int* __restrict__ top_idx)
{
    __shared__ u32 hist[256];
    __shared__ u32 scan[256];
    __shared__ u32 sel_byte, sel_above;
    const int tid = threadIdx.x;
    const size_t row = blockIdx.x;
    const u32* src = keys_g + row * NS;

    u32 keys[8];
    #pragma unroll
    for (int i = 0; i < 8; ++i) keys[i] = src[tid*8 + i];

    u32 prefix = 0, kk = NTOPK, total_gt = 0;
    #pragma unroll
    for (int pass = 0; pass < 4; ++pass) {
        const int shift = 24 - pass*8;
        const u32 mask_hi = (pass == 0) ? 0u : (0xFFFFFFFFu << (shift + 8));
        hist[tid] = 0;
        __syncthreads();
        #pragma unroll
        for (int i = 0; i < 8; ++i)
            if (((keys[i] ^ prefix) & mask_hi) == 0u)
                atomicAdd(&hist[(keys[i] >> shift) & 255], 1u);
        __syncthreads();
        // inclusive suffix scan over 256 bins, by wave 0 only
        if (tid < 64) {
            u32 v0 = hist[tid*4+0], v1 = hist[tid*4+1], v2 = hist[tid*4+2], v3 = hist[tid*4+3];
            u32 s3 = v3, s2 = v2 + s3, s1 = v1 + s2, s0 = v0 + s1;
            u32 suf = s0;
            #pragma unroll
            for (int o = 1; o < 64; o <<= 1) {
                u32 t = __shfl_down(suf, o, 64);
                if (tid + o < 64) suf += t;
            }
            u32 excl = suf - s0;   // sum over lanes > tid (u32-exact)
            hist[tid*4+0] = s0 + excl;
            hist[tid*4+1] = s1 + excl;
            hist[tid*4+2] = s2 + excl;
            hist[tid*4+3] = s3 + excl;
        }
        __syncthreads();
        if (hist[tid] >= kk && (tid == 255 || hist[tid+1] < kk)) {
            sel_byte = (u32)tid;
            sel_above = (tid == 255) ? 0u : hist[tid+1];
        }
        __syncthreads();
        u32 sb = sel_byte, sa = sel_above;
        prefix |= (sb << shift);
        total_gt += sa;
        kk -= sa;
    }

    const u32 T = prefix;
    const u32 needed = NTOPK - total_gt;

    u32 cgt = 0, ceq = 0;
    #pragma unroll
    for (int i = 0; i < 8; ++i) { cgt += (keys[i] > T); ceq += (keys[i] == T); }
    scan[tid] = (cgt << 16) | ceq;
    __syncthreads();
    // inclusive prefix scan over 256 threads, by wave 0 only
    if (tid < 64) {
        u32 v0 = scan[tid*4+0], v1 = scan[tid*4+1], v2 = scan[tid*4+2], v3 = scan[tid*4+3];
        u32 p0 = v0, p1 = p0 + v1, p2 = p1 + v2, p3 = p2 + v3;
        u32 pre = p3;
        #pragma unroll
        for (int o = 1; o < 64; o <<= 1) {
            u32 t = __shfl_up(pre, o, 64);
            if (tid >= o) pre += t;
        }
        u32 excl = pre - p3;   // sum over lanes < tid
        scan[tid*4+0] = p0 + excl;
        scan[tid*4+1] = p1 + excl;
        scan[tid*4+2] = p2 + excl;
        scan[tid*4+3] = p3 + excl;
    }
    __syncthreads();
    u32 incl = scan[tid];
    u32 gt_pref = (incl >> 16) - cgt;
    u32 eq_pref = (incl & 0xFFFFu) - ceq;

    int* dst = top_idx + row * NTOPK;
    u32 lgt = 0, leq = 0;
    #pragma unroll
    for (int i = 0; i < 8; ++i) {
        int idx = tid*8 + i;
        if (keys[i] > T) {
            u32 eqsel = eq_pref + leq; if (eqsel > needed) eqsel = needed;
            u32 slot = gt_pref + lgt + eqsel;
            if (slot < NTOPK) dst[slot] = idx;
            lgt++;
        } else if (keys[i] == T) {
            u32 er = eq_pref + leq;
            if (er < needed) {
                u32 slot = gt_pref + lgt + er;
                if (slot < NTOPK) dst[slot] = idx;
            }
            leq++;
        }
    }
}

// ============================ Kernel 4 =====================================
// Gathered attention, split-bf16 3-term MFMA, precomputed Khl/Vhl.
__global__ __launch_bounds__(256) void k4_attn_mfma(
    const float* __restrict__ Qg, const short* __restrict__ Khl, const short* __restrict__ Vhl,
    const int* __restrict__ top_idx, float* __restrict__ out)
{
    __shared__ short Ph[NTOPK*16];  // P^T hi [key][head] 16 KB
    __shared__ short Pl[NTOPK*16];  // 16 KB
    __shared__ short Vh[64*64];     // V chunk, subtiled-swizzled, 8 KB
    __shared__ short Vl[64*64];     // 8 KB
    __shared__ float red[2][16][4];
    __shared__ int   idxs[NTOPK];

    const int tid = threadIdx.x;
    const int l = tid & 63, w = tid >> 6;
    const int q = l >> 4, d15 = l & 15;
    const size_t blk = blockIdx.x;
    const int b = (int)(blk >> 11), s = (int)(blk & 2047);

    for (int i = tid; i < NTOPK; i += 256) idxs[i] = top_idx[blk*NTOPK + i];

    // Q A-fragments: row(head)=d15, k = ks*32 + q*8 + j
    bf16x8 qhi[2], qlo[2];
    {
        const float* qp = Qg + (((size_t)b*NH + d15)*NS + s)*NDK + q*8;
        #pragma unroll
        for (int ks = 0; ks < 2; ++ks) {
            float4 f0 = *reinterpret_cast<const float4*>(qp + ks*32);
            float4 f1 = *reinterpret_cast<const float4*>(qp + ks*32 + 4);
            float fv[8] = {f0.x,f0.y,f0.z,f0.w,f1.x,f1.y,f1.z,f1.w};
            #pragma unroll
            for (int jj = 0; jj < 8; ++jj) {
                short hh = f2bf(fv[jj]);
                qhi[ks][jj] = hh;
                qlo[ks][jj] = f2bf(fv[jj] - bf2f(hh));
            }
        }
    }
    __syncthreads();   // idxs ready

    f32x4 sacc[8];
    #pragma unroll
    for (int t = 0; t < 8; ++t) sacc[t] = (f32x4){0.f, 0.f, 0.f, 0.f};

    // ---- QK^T: direct global gather of K fragments ----
    #pragma unroll
    for (int c = 0; c < 4; ++c) {
        #pragma unroll
        for (int t = 0; t < 2; ++t) {
            int key = c*128 + w*32 + t*16 + d15;
            int kidx = idxs[key];
            const short* rowp = Khl + ((size_t)b*NS + kidx)*128;
            int ti = c*2 + t;
            #pragma unroll
            for (int ks = 0; ks < 2; ++ks) {
                bf16x8 kh = *reinterpret_cast<const bf16x8*>(rowp + ks*32 + q*8);
                bf16x8 kl = *reinterpret_cast<const bf16x8*>(rowp + 64 + ks*32 + q*8);
                sacc[ti] = __builtin_amdgcn_mfma_f32_16x16x32_bf16(qhi[ks], kh, sacc[ti], 0, 0, 0);
                sacc[ti] = __builtin_amdgcn_mfma_f32_16x16x32_bf16(qlo[ks], kh, sacc[ti], 0, 0, 0);
                sacc[ti] = __builtin_amdgcn_mfma_f32_16x16x32_bf16(qhi[ks], kl, sacc[ti], 0, 0, 0);
            }
        }
    }

    // ---- prefetch V chunk 0 into regs ----
    bf16x8 vreg[4];
    #pragma unroll
    for (int i = 0; i < 4; ++i) {
        int tt = tid + 256*(i & 3);
        int key = (tt >> 3) & 63, jb = tt & 7, part = tt >> 9;
        vreg[i] = *reinterpret_cast<const bf16x8*>(
            Vhl + ((size_t)b*NS + idxs[0*64 + key])*128 + part*64 + jb*8);
    }

    // ---- softmax: head = q*4 + rg, distributed over 4 waves ----
    float m[4], inv[4];
    #pragma unroll
    for (int rg = 0; rg < 4; ++rg) {
        float mm = -3.4e38f;
        #pragma unroll
        for (int t = 0; t < 8; ++t) { sacc[t][rg] *= 0.125f; mm = fmaxf(mm, sacc[t][rg]); }
        #pragma unroll
        for (int o = 1; o <= 8; o <<= 1) mm = fmaxf(mm, __shfl_xor(mm, o));
        m[rg] = mm;
    }
    if (d15 == 0) {
        #pragma unroll
        for (int rg = 0; rg < 4; ++rg) red[0][q*4 + rg][w] = m[rg];
    }
    __syncthreads();
    float sum[4];
    #pragma unroll
    for (int rg = 0; rg < 4; ++rg) {
        int hh = q*4 + rg;
        float g = fmaxf(fmaxf(red[0][hh][0], red[0][hh][1]),
                        fmaxf(red[0][hh][2], red[0][hh][3]));
        float ss = 0.f;
        #pragma unroll
        for (int t = 0; t < 8; ++t) { float p = __expf(sacc[t][rg] - g); sacc[t][rg] = p; ss += p; }
        #pragma unroll
        for (int o = 1; o <= 8; o <<= 1) ss += __shfl_xor(ss, o);
        sum[rg] = ss;
    }
    if (d15 == 0) {
        #pragma unroll
        for (int rg = 0; rg < 4; ++rg) red[1][q*4 + rg][w] = sum[rg];
    }
    __syncthreads();
    #pragma unroll
    for (int rg = 0; rg < 4; ++rg) {
        int hh = q*4 + rg;
        inv[rg] = 1.f / (red[1][hh][0] + red[1][hh][1] + red[1][hh][2] + red[1][hh][3]);
    }

    // ---- write P transposed [key][16 heads], split bf16, b64 writes ----
    #pragma unroll
    for (int t = 0; t < 8; ++t) {
        int key = (t >> 1)*128 + w*32 + (t & 1)*16 + d15;
        bf16x4 h4, l4;
        #pragma unroll
        for (int rg = 0; rg < 4; ++rg) {
            float p = sacc[t][rg] * inv[rg];
            short ph_ = f2bf(p);
            h4[rg] = ph_;
            l4[rg] = f2bf(p - bf2f(ph_));
        }
        *reinterpret_cast<bf16x4*>(&Ph[key*16 + q*4]) = h4;
        *reinterpret_cast<bf16x4*>(&Pl[key*16 + q*4]) = l4;
    }

    // write prefetched V chunk 0
    #pragma unroll
    for (int i = 0; i < 4; ++i) {
        int tt = tid + 256*(i & 3);
        int key = (tt >> 3) & 63, jb = tt & 7, part = tt >> 9;
        short* dstp = (part ? Vl : Vh) + key*64 + (((jb*2) ^ ((key & 3) << 2)) * 4);
        *reinterpret_cast<bf16x8*>(dstp) = vreg[i];
    }
    __syncthreads();

    const unsigned phb = (unsigned)(size_t)&Ph[0];
    const unsigned plb = (unsigned)(size_t)&Pl[0];
    const unsigned vhb = (unsigned)(size_t)&Vh[0];
    const unsigned vlb = (unsigned)(size_t)&Vl[0];

    // ---- PV over 8 chunks of 64 keys ----
    f32x4 oacc = (f32x4){0.f, 0.f, 0.f, 0.f};
    #pragma unroll
    for (int c = 0; c < 8; ++c) {
        if (c < 7) {
            #pragma unroll
            for (int i = 0; i < 4; ++i) {
                int tt = tid + 256*(i & 3);
                int key = (tt >> 3) & 63, jb = tt & 7, part = tt >> 9;
                vreg[i] = *reinterpret_cast<const bf16x8*>(
                    Vhl + ((size_t)b*NS + idxs[(c+1)*64 + key])*128 + part*64 + jb*8);
            }
        }
        #pragma unroll
        for (int ks = 0; ks < 2; ++ks) {
            unsigned pa = phb + (unsigned)((c*64 + ks*32 + 8*q + (d15 >> 2))*32 + (d15 & 3)*8);
            unsigned pla = pa + (plb - phb);
            unsigned va = vhb + (unsigned)((ks*32 + 8*q + (d15 >> 2))*128
                                           + (((w*4 + (d15 & 3)) ^ ((d15 >> 2) << 2)) * 8));
            unsigned vla = va + (vlb - vhb);
            bf16x4 p0, p1, r0, r1, v0, v1, u0, u1;
            TR64(p0, pa,  "0");   TR64(p1, pa,  "128");
            TR64(r0, pla, "0");   TR64(r1, pla, "128");
            TR64(v0, va,  "0");   TR64(v1, va,  "512");
            TR64(u0, vla, "0");   TR64(u1, vla, "512");
            asm volatile("s_waitcnt lgkmcnt(0)" ::: "memory");
            __builtin_amdgcn_sched_barrier(0);
            bf16x8 pH = __builtin_shufflevector(p0, p1, 0,1,2,3,4,5,6,7);
            bf16x8 pL = __builtin_shufflevector(r0, r1, 0,1,2,3,4,5,6,7);
            bf16x8 vH = __builtin_shufflevector(v0, v1, 0,1,2,3,4,5,6,7);
            bf16x8 vL = __builtin_shufflevector(u0, u1, 0,1,2,3,4,5,6,7);
            oacc = __builtin_amdgcn_mfma_f32_16x16x32_bf16(pH, vH, oacc, 0, 0, 0);
            oacc = __builtin_amdgcn_mfma_f32_16x16x32_bf16(pL, vH, oacc, 0, 0, 0);
            oacc = __builtin_amdgcn_mfma_f32_16x16x32_bf16(pH, vL, oacc, 0, 0, 0);
        }
        if (c < 7) {
            __syncthreads();
            #pragma unroll
            for (int i = 0; i < 4; ++i) {
                int tt = tid + 256*(i & 3);
                int key = (tt >> 3) & 63, jb = tt & 7, part = tt >> 9;
                short* dstp = (part ? Vl : Vh) + key*64 + (((jb*2) ^ ((key & 3) << 2)) * 4);
                *reinterpret_cast<bf16x8*>(dstp) = vreg[i];
            }
            __syncthreads();
        }
    }

    #pragma unroll
    for (int rg = 0; rg < 4; ++rg) {
        int hh = q*4 + rg;
        out[((size_t)b*NS + s)*(NH*NDK) + hh*NDK + w*16 + d15] = oacc[rg];
    }
    if (blk == 0 && tid == 0) out[(size_t)NB*NS*NH*NDK] = 0.f;  // kl_loss
}

// ============================ launch =======================================
extern "C" void kernel_launch(void* const* d_in, const int* in_sizes, int n_in,
                              void* d_out, int out_size, void* d_ws, size_t ws_size,
                              hipStream_t stream) {
    const float* x     = (const float*)d_in[0];
    const float* Q     = (const float*)d_in[1];
    const float* K     = (const float*)d_in[2];
    const float* V     = (const float*)d_in[3];
    const float* Wq    = (const float*)d_in[4];
    const float* bq    = (const float*)d_in[5];
    const float* Wk    = (const float*)d_in[6];
    const float* bk    = (const float*)d_in[7];
    const float* gamma = (const float*)d_in[8];
    const float* beta  = (const float*)d_in[9];
    const float* hw    = (const float*)d_in[10];
    float* outp = (float*)d_out;

    // ws layout (44 MB):
    //   [0, 4.19M)     : q_index fp32  (top_idx aliased here after k2)
    //   [4.19, 8.39M)  : k_index fp32
    //   [8.39, 41.9M)  : keys u32
    //   [41.9, 42.9M)  : Khl bf16 hi/lo
    //   [42.9, 44.0M)  : Vhl bf16 hi/lo
    float* q_index = (float*)d_ws;
    float* k_index = q_index + (size_t)NB*NS*NHI*NDI;
    u32*   keys    = (u32*)(k_index + (size_t)NB*NS*NHI*NDI);
    short* Khl     = (short*)(keys + (size_t)NB*NS*NS);
    short* Vhl     = Khl + (size_t)NB*NS*128;
    int*   top_idx = (int*)d_ws;              // aliases q/k region (dead after k2)

    k0_split<<<(NB*NS*NDK)/256, 256, 0, stream>>>(K, V, Khl, Vhl);
    k1_proj_ln<<<(NB*NS/ROWS1)*2, 256, 0, stream>>>(x, Wq, bq, Wk, bk, gamma, beta, q_index, k_index);
    k2_scores<<<dim3(NS/64, NS/64, NB), 256, 0, stream>>>(q_index, k_index, hw, keys);
    k3_select<<<NB*NS, 256, 0, stream>>>(keys, top_idx);
    k4_attn_mfma<<<NB*NS, 256, 0, stream>>>(Q, Khl, Vhl, top_idx, outp);
}